// Round 5
// baseline (125.283 us; speedup 1.0000x reference)
//
#include <hip/hip_runtime.h>
#include <math.h>

#define NROW 384
#define NCOL 512
#define SLICE 196608          // 384*512

// ---------------------------------------------------------------------------
// ws layout (float offsets):
//   hp  : 16 x SLICE @ 0         layer-1 partials [br*8 + slice]
//   gp  : 16 x SLICE @ 3145728   layer-2 partials [br*8 + slice]
//   m1p : 12*512     @ 6291456   y column-sum partials
//   m2p : 12*512     @ 6297600   y column-sumsq partials
//   m1  : 512        @ 6303744   reduced column sums
//   m2  : 512        @ 6304256
//   part: 192 dbl    @ 6304768   (byte 25219072, 8B aligned)
//   cnt : 1 int      @ 6305152
// total ~25.2 MB (L2/L3 resident)
// ---------------------------------------------------------------------------
#define HP_OFF   0
#define GP_OFF   3145728
#define M1P_OFF  6291456
#define M2P_OFF  6297600
#define M1_OFF   6303744
#define M2_OFF   6304256
#define PART_OFF 6304768
#define CNT_OFF  6305152

// GEMM block: C[64x128] = A[64 x 64 k-slice] @ W[64 x 128 slice].
// 128 threads (2 waves), 8x8 micro-tile => 1 B LDS-read per MAC (the LDS pipe
// is the fp32-GEMM bottleneck: ~85 B/cyc/CU vs 128 MAC/cyc VALU).
// Whole K-slice staged once -> single barrier per block; latency hidden by
// 3 co-resident blocks/CU (49 KB LDS each).
// NS=1: A read directly. NS=8: A = relu(sum of 8 slices + bias1[k]).
template<int NS>
__device__ __forceinline__ void gemm64x128(
    const float* __restrict__ A, const float* __restrict__ bias1,
    const float* __restrict__ W, float* __restrict__ C,
    int m0, int n0, int ca)
{
    __shared__ __align__(16) float As[64][68];   // k-major, pad 68
    __shared__ __align__(16) float Bs[64][128];  // natural, unpadded

    const int t = threadIdx.x;

    // ---- stage A (transpose to k-major): thread owns row t&63, k-half t>>6
    {
        const int arow  = t & 63;
        const int ahalf = t >> 6;                 // 0/1 -> k 0..31 / 32..63
        const float* ap = &A[(size_t)(m0 + arow) * NCOL + ca + ahalf * 32];
        #pragma unroll
        for (int g = 0; g < 8; ++g) {
            float v[4];
            if (NS == 1) {
                *(float4*)v = *(const float4*)(ap + g * 4);
            } else {
                float s4[4] = {0.f, 0.f, 0.f, 0.f};
                #pragma unroll
                for (int s = 0; s < NS; ++s) {
                    float u[4];
                    *(float4*)u = *(const float4*)(ap + (size_t)s * SLICE + g * 4);
                    s4[0] += u[0]; s4[1] += u[1]; s4[2] += u[2]; s4[3] += u[3];
                }
                float bb[4];
                *(float4*)bb = *(const float4*)&bias1[ca + ahalf * 32 + g * 4];
                v[0] = fmaxf(s4[0] + bb[0], 0.f);
                v[1] = fmaxf(s4[1] + bb[1], 0.f);
                v[2] = fmaxf(s4[2] + bb[2], 0.f);
                v[3] = fmaxf(s4[3] + bb[3], 0.f);
            }
            const int k = ahalf * 32 + g * 4;
            As[k + 0][arow] = v[0];
            As[k + 1][arow] = v[1];
            As[k + 2][arow] = v[2];
            As[k + 3][arow] = v[3];
        }
    }

    // ---- stage B: linear f4 mapping, coalesced global loads + linear stores
    #pragma unroll
    for (int i = 0; i < 16; ++i) {
        const int f4 = t + i * 128;               // 0..2047
        const int kk = f4 >> 5;
        const int c4 = (f4 & 31) * 4;
        *(float4*)&Bs[kk][c4] =
            *(const float4*)&W[(size_t)(ca + kk) * NCOL + n0 + c4];
    }
    __syncthreads();

    // ---- compute: micro 8x8. rows ty*8+i; cols tx*4+j and 64+tx*4+j
    const int ty = t >> 4, tx = t & 15;
    float acc[8][8] = {};
    #pragma unroll 16
    for (int kk = 0; kk < 64; ++kk) {
        float a[8], b[8];
        *(float4*)&a[0] = *(const float4*)&As[kk][ty * 8];       // ds_read_b128
        *(float4*)&a[4] = *(const float4*)&As[kk][ty * 8 + 4];
        *(float4*)&b[0] = *(const float4*)&Bs[kk][tx * 4];       // 16B-stride, 2-way=free
        *(float4*)&b[4] = *(const float4*)&Bs[kk][64 + tx * 4];
        #pragma unroll
        for (int i = 0; i < 8; ++i)
            #pragma unroll
            for (int j = 0; j < 8; ++j)
                acc[i][j] += a[i] * b[j];
    }

    // ---- write K-slice partial
    #pragma unroll
    for (int i = 0; i < 8; ++i) {
        const size_t row = (size_t)(m0 + ty * 8 + i) * NCOL;
        *(float4*)&C[row + n0 + tx * 4] =
            make_float4(acc[i][0], acc[i][1], acc[i][2], acc[i][3]);
        *(float4*)&C[row + n0 + 64 + tx * 4] =
            make_float4(acc[i][4], acc[i][5], acc[i][6], acc[i][7]);
    }
}

// Kernel 1: layer-1 GEMM partials (384 blocks: 8sl x 2br x 24 tiles)
// + 12 y column-moment blocks.
__global__ __launch_bounds__(128, 2) void k_layer1(
    const float* __restrict__ x,
    const float* __restrict__ w1mu, const float* __restrict__ w1lv,
    const float* __restrict__ y, float* __restrict__ ws)
{
    const int b = blockIdx.x;
    const int t = threadIdx.x;

    if (b >= 384) {
        // y column moments: 32 rows per block, thread owns 4 columns
        const int sb = b - 384;
        const int c  = t * 4;
        float s1[4] = {0.f, 0.f, 0.f, 0.f};
        float s2[4] = {0.f, 0.f, 0.f, 0.f};
        #pragma unroll 4
        for (int r = 0; r < 32; ++r) {
            float v[4];
            *(float4*)v = *(const float4*)&y[(size_t)(sb * 32 + r) * NCOL + c];
            #pragma unroll
            for (int j = 0; j < 4; ++j) { s1[j] += v[j]; s2[j] += v[j] * v[j]; }
        }
        *(float4*)&ws[M1P_OFF + sb * NCOL + c] = make_float4(s1[0], s1[1], s1[2], s1[3]);
        *(float4*)&ws[M2P_OFF + sb * NCOL + c] = make_float4(s2[0], s2[1], s2[2], s2[3]);
        return;
    }

    const int sl   = b & 7;            // K-slice
    const int br   = (b >> 3) & 1;
    const int tile = b >> 4;           // 0..23
    const int mt   = tile >> 2;        // 6 M-tiles of 64
    const int nt   = tile & 3;         // 4 N-tiles of 128

    gemm64x128<1>(x, nullptr, br ? w1lv : w1mu,
                  ws + HP_OFF + (size_t)(br * 8 + sl) * SLICE,
                  mt * 64, nt * 128, sl * 64);
}

// Kernel 2: layer-2 GEMM partials; A-loader fuses relu(sum8 + b1).
// Block 384 reduces the y-stat partials and zeroes the k3 counter.
__global__ __launch_bounds__(128, 2) void k_layer2(
    const float* __restrict__ b1mu, const float* __restrict__ b1lv,
    const float* __restrict__ w2mu, const float* __restrict__ w2lv,
    float* __restrict__ ws)
{
    const int b = blockIdx.x;
    const int t = threadIdx.x;

    if (b == 384) {
        if (t == 0) *(int*)(ws + CNT_OFF) = 0;
        const int c = t * 4;
        float s1[4] = {0.f, 0.f, 0.f, 0.f};
        float s2[4] = {0.f, 0.f, 0.f, 0.f};
        #pragma unroll
        for (int p = 0; p < 12; ++p) {
            float p1[4], p2[4];
            *(float4*)p1 = *(const float4*)&ws[M1P_OFF + p * NCOL + c];
            *(float4*)p2 = *(const float4*)&ws[M2P_OFF + p * NCOL + c];
            #pragma unroll
            for (int j = 0; j < 4; ++j) { s1[j] += p1[j]; s2[j] += p2[j]; }
        }
        *(float4*)&ws[M1_OFF + c] = make_float4(s1[0], s1[1], s1[2], s1[3]);
        *(float4*)&ws[M2_OFF + c] = make_float4(s2[0], s2[1], s2[2], s2[3]);
        return;
    }

    const int sl   = b & 7;
    const int br   = (b >> 3) & 1;
    const int tile = b >> 4;
    const int mt   = tile >> 2;
    const int nt   = tile & 3;

    gemm64x128<8>(ws + HP_OFF + (size_t)(br * 8) * SLICE,
                  br ? b1lv : b1mu, br ? w2lv : w2mu,
                  ws + GP_OFF + (size_t)(br * 8 + sl) * SLICE,
                  mt * 64, nt * 128, sl * 64);
}

// Kernel 3: elementwise epilogue (sums 8 layer-2 slices) + block reduction +
// last-block final reduce. 192 blocks x 256 threads, 1 float4 per thread.
__global__ __launch_bounds__(256) void k_epilogue(
    const float* __restrict__ b2mu, const float* __restrict__ b2lv,
    const float* __restrict__ y, float* __restrict__ ws,
    float* __restrict__ out)
{
    __shared__ double wsum[4];
    __shared__ int is_last;

    const int t = threadIdx.x;
    const float inv_b = 1.0f / (float)NROW;

    const int e4   = blockIdx.x * 256 + t;
    const int col4 = e4 & 127;
    const size_t off = (size_t)e4 * 4;

    const float* gpm = ws + GP_OFF;                 // mu slices 0..7
    const float* gpl = ws + GP_OFF + 8 * (size_t)SLICE;  // lv slices 0..7

    float gm[4] = {0.f, 0.f, 0.f, 0.f};
    float gl[4] = {0.f, 0.f, 0.f, 0.f};
    #pragma unroll
    for (int s = 0; s < 8; ++s) {
        float a[4], c[4];
        *(float4*)a = *(const float4*)&gpm[(size_t)s * SLICE + off];
        *(float4*)c = *(const float4*)&gpl[(size_t)s * SLICE + off];
        #pragma unroll
        for (int j = 0; j < 4; ++j) { gm[j] += a[j]; gl[j] += c[j]; }
    }

    float yv[4], bm[4], bl[4], m1v[4], m2v[4];
    *(float4*)yv  = *(const float4*)&y[off];
    *(float4*)bm  = *(const float4*)&b2mu[col4 * 4];
    *(float4*)bl  = *(const float4*)&b2lv[col4 * 4];
    *(float4*)m1v = *(const float4*)&ws[M1_OFF + col4 * 4];
    *(float4*)m2v = *(const float4*)&ws[M2_OFF + col4 * 4];

    float tsum = 0.f;
    #pragma unroll
    for (int j = 0; j < 4; ++j) {
        const float m1 = m1v[j] * inv_b;
        const float m2 = m2v[j] * inv_b;
        const float mu = gm[j] + bm[j];
        const float lv = tanhf(gl[j] + bl[j]);
        const float iv = expf(-lv);
        tsum += iv * ((yv[j] * yv[j] - m2) + 2.f * mu * (m1 - yv[j]));
    }

    float s = tsum;
    #pragma unroll
    for (int o = 32; o > 0; o >>= 1) s += __shfl_down(s, o);
    if ((t & 63) == 0) wsum[t >> 6] = (double)s;
    __syncthreads();

    double* partials = (double*)(ws + PART_OFF);
    int* counter = (int*)(ws + CNT_OFF);
    if (t == 0) {
        partials[blockIdx.x] = wsum[0] + wsum[1] + wsum[2] + wsum[3];
        __threadfence();
        const int old = atomicAdd(counter, 1);
        is_last = (old == 191) ? 1 : 0;
    }
    __syncthreads();

    if (is_last && t < 64) {
        __threadfence();
        double v = partials[t] + partials[t + 64] + partials[t + 128];
        #pragma unroll
        for (int o = 32; o > 0; o >>= 1) v += __shfl_down(v, o);
        if (t == 0) {
            // C0 = log1p(exp(-20)/383) — the broadcast-bug logsumexp constant
            const double C0 = 5.381602146862063e-12;
            out[0] = (float)(-0.5 * v / (double)NROW - C0);
        }
    }
}

extern "C" void kernel_launch(void* const* d_in, const int* in_sizes, int n_in,
                              void* d_out, int out_size, void* d_ws, size_t ws_size,
                              hipStream_t stream) {
    const float* x    = (const float*)d_in[0];
    const float* y    = (const float*)d_in[1];
    const float* w1mu = (const float*)d_in[2];
    const float* b1mu = (const float*)d_in[3];
    const float* w2mu = (const float*)d_in[4];
    const float* b2mu = (const float*)d_in[5];
    const float* w1lv = (const float*)d_in[6];
    const float* b1lv = (const float*)d_in[7];
    const float* w2lv = (const float*)d_in[8];
    const float* b2lv = (const float*)d_in[9];
    float* out = (float*)d_out;
    float* ws  = (float*)d_ws;

    k_layer1<<<396, 128, 0, stream>>>(x, w1mu, w1lv, y, ws);
    k_layer2<<<385, 128, 0, stream>>>(b1mu, b1lv, w2mu, w2lv, ws);
    k_epilogue<<<192, 256, 0, stream>>>(b2mu, b2lv, y, ws, out);
}